// Round 4
// baseline (2454.937 us; speedup 1.0000x reference)
//
#include <hip/hip_runtime.h>
#include <hip/hip_fp16.h>

typedef unsigned short u16;
typedef unsigned int   u32;

#define DIM    64
#define NREL   8
#define NB     4
#define NNODE  150000
#define NEDGE  1000000
#define NSEDGE 200000
#define BATCH  1024
#define SEQL   20
#define NPRED  20
#define TD     384
#define TRASH  NNODE            // dummy-edge dst row (never read)

__device__ __forceinline__ u32 packh2(float lo, float hi) {
    __half2 h;
    h.x = __float2half_rn(lo);
    h.y = __float2half_rn(hi);
    u32 r;
    __builtin_memcpy(&r, &h, 4);
    return r;
}
__device__ __forceinline__ float2 h2pair(u32 w) {
    __half2 h;
    __builtin_memcpy(&h, &w, 4);
    return __half22float2(h);
}

// =================== counting sort of edges by relation ===================

__global__ __launch_bounds__(256) void fill_kernel(int* __restrict__ sidx, int n) {
    int i = blockIdx.x * 256 + threadIdx.x, st = gridDim.x * 256;
    for (; i < n; i += st) sidx[i] = -1;      // -1 = dummy pad slot
}

__global__ __launch_bounds__(256) void hist_kernel(const int* __restrict__ et, int E,
                                                   int* __restrict__ gcnt) {
    __shared__ int h[NREL];
    if (threadIdx.x < NREL) h[threadIdx.x] = 0;
    __syncthreads();
    int i = blockIdx.x * 256 + threadIdx.x, st = gridDim.x * 256;
    for (; i < E; i += st) atomicAdd(&h[et[i]], 1);
    __syncthreads();
    if (threadIdx.x < NREL) atomicAdd(&gcnt[threadIdx.x], h[threadIdx.x]);
}

// single thread: padded (multiple-of-8) exclusive prefix for both lists
__global__ void offs_kernel(const int* __restrict__ cntB, const int* __restrict__ cntS,
                            int* __restrict__ poffB, int* __restrict__ poffS) {
    if (threadIdx.x == 0 && blockIdx.x == 0) {
        int a = 0, b = 0;
        poffB[0] = 0; poffS[0] = 0;
        for (int r = 0; r < NREL; ++r) {
            a += (cntB[r] + 7) & ~7; poffB[r + 1] = a;
            b += (cntS[r] + 7) & ~7; poffS[r + 1] = b;
        }
    }
}

// block-aggregated scatter of edge indices into relation buckets
__global__ __launch_bounds__(256) void scatter_kernel(const int* __restrict__ et, int E,
                                                      int* __restrict__ cur,
                                                      const int* __restrict__ poff,
                                                      int* __restrict__ sidx) {
    __shared__ int bcnt[NREL], bbase[NREL], lcur[NREL];
    if (threadIdx.x < NREL) { bcnt[threadIdx.x] = 0; lcur[threadIdx.x] = 0; }
    __syncthreads();
    const int chunk = (E + gridDim.x - 1) / gridDim.x;
    const int lo = blockIdx.x * chunk;
    const int hi = (lo + chunk < E) ? lo + chunk : E;
    for (int e = lo + threadIdx.x; e < hi; e += 256) atomicAdd(&bcnt[et[e]], 1);
    __syncthreads();
    if (threadIdx.x < NREL)
        bbase[threadIdx.x] = atomicAdd(&cur[threadIdx.x], bcnt[threadIdx.x]);
    __syncthreads();
    for (int e = lo + threadIdx.x; e < hi; e += 256) {
        const int r = et[e];
        const int loc = atomicAdd(&lcur[r], 1);
        sidx[poff[r] + bbase[r] + loc] = e;
    }
}

// =================== weight packing ===================
// Wp row (r,l): 32 u32; storage slot s (16B chunk) holds data chunk c = s ^ (l&7)
// (pre-swizzled so the reader's ds_read_b128 is bank-conflict-free at 64 KB, no pad).
// element: packh2( W[r][d][jj], W[r][d][jj+32] ), d = (l>>5)*32 + p, jj = l&31.
__global__ __launch_bounds__(256) void wpack_kernel(const float* __restrict__ comp,
                                                    const float* __restrict__ basis,
                                                    u32* __restrict__ Wp) {
    int idx = blockIdx.x * 256 + threadIdx.x;     // NREL*64*32 = 16384
    int r = idx >> 11;
    int l = (idx >> 5) & 63;
    int pp = idx & 31;                            // storage position
    int s = pp >> 2, i = pp & 3;
    int c = s ^ (l & 7);                          // data chunk
    int p = c * 4 + i;
    int jj = l & 31;
    int d = (l >> 5) * 32 + p;
    float c0 = comp[r * NB + 0], c1 = comp[r * NB + 1];
    float c2 = comp[r * NB + 2], c3 = comp[r * NB + 3];
    const float* b = basis + d * 64;
    float lo = c0 * b[jj]      + c1 * b[4096 + jj]      + c2 * b[8192 + jj]      + c3 * b[12288 + jj];
    float hi = c0 * b[jj + 32] + c1 * b[4096 + jj + 32] + c2 * b[8192 + jj + 32] + c3 * b[12288 + jj + 32];
    Wp[(r * 64 + l) * 32 + pp] = packh2(lo, hi);
}

// root: linear layout, read from global by node_kernel (no LDS): Rp[l*32+p]
__global__ __launch_bounds__(256) void rpack_kernel(const float* __restrict__ root,
                                                    u32* __restrict__ Rp) {
    int idx = blockIdx.x * 256 + threadIdx.x;     // 2048
    if (idx >= 2048) return;
    int l = idx >> 5, p = idx & 31;
    int jj = l & 31;
    int d = (l >> 5) * 32 + p;
    Rp[idx] = packh2(root[d * 64 + jj], root[d * 64 + jj + 32]);
}

// =================== edge transform + scatter ===================
// Batches of 8 same-relation (sorted) edges per wave. W fragment: 8 ds_read_b128
// per batch, unpacked once to 32 float2 regs. Per edge: 8 bcast float4 x-loads,
// 64 fma (float2), shfl-combine halves, 1 coalesced atomicAdd per lane.
__global__ __launch_bounds__(512, 4) void edge_kernel(const float* __restrict__ x,
                                                      const u32* __restrict__ Wp,
                                                      const int* __restrict__ sidx,
                                                      const int* __restrict__ esrc,
                                                      const int* __restrict__ edst,
                                                      const int* __restrict__ poff,
                                                      float* __restrict__ agg) {
    __shared__ u32 Wl[NREL * 64 * 32];            // 64 KB -> 2 blocks/CU
    {
        const uint4* gs = (const uint4*)Wp;
        uint4* ls = (uint4*)Wl;
        for (int i = threadIdx.x; i < NREL * 64 * 32 / 4; i += 512) ls[i] = gs[i];
    }
    __syncthreads();
    const int lane = threadIdx.x & 63;
    const int hf = lane >> 5;
    const int p1 = poff[1], p2 = poff[2], p3 = poff[3], p4 = poff[4];
    const int p5 = poff[5], p6 = poff[6], p7 = poff[7];
    const int nb = poff[8] >> 3;                  // number of 8-edge batches
    int wave = blockIdx.x * 8 + (threadIdx.x >> 6);
    const int nw = gridDim.x * 8;
    for (int b = wave; b < nb; b += nw) {
        const int e0 = b * 8;
        const int r = (e0 >= p1) + (e0 >= p2) + (e0 >= p3) + (e0 >= p4) +
                      (e0 >= p5) + (e0 >= p6) + (e0 >= p7);
        const u32* wrow = &Wl[(r * 64 + lane) * 32];
        const int sw = (lane & 7) << 2;
        float2 wv[32];
#pragma unroll
        for (int c = 0; c < 8; ++c) {             // de-swizzle: chunk c at slot c^(lane&7)
            const uint4 wq = *(const uint4*)(wrow + ((c << 2) ^ sw));
            wv[c * 4 + 0] = h2pair(wq.x); wv[c * 4 + 1] = h2pair(wq.y);
            wv[c * 4 + 2] = h2pair(wq.z); wv[c * 4 + 3] = h2pair(wq.w);
        }
        for (int e = e0; e < e0 + 8; ++e) {
            const int idx = sidx[e];
            int s, dn;
            if (idx >= 0) { s = esrc[idx]; dn = edst[idx]; }
            else          { s = 0; dn = TRASH; }  // bucket pad (wave-uniform branch)
            const float* xr = x + (size_t)s * 64 + hf * 32;
            float aL = 0.f, aH = 0.f;
#pragma unroll
            for (int q = 0; q < 8; ++q) {
                const float4 xv = *(const float4*)(xr + q * 4);
                aL += xv.x * wv[q * 4 + 0].x; aH += xv.x * wv[q * 4 + 0].y;
                aL += xv.y * wv[q * 4 + 1].x; aH += xv.y * wv[q * 4 + 1].y;
                aL += xv.z * wv[q * 4 + 2].x; aH += xv.z * wv[q * 4 + 2].y;
                aL += xv.w * wv[q * 4 + 3].x; aH += xv.w * wv[q * 4 + 3].y;
            }
            aL += __shfl_xor(aL, 32, 64);
            aH += __shfl_xor(aH, 32, 64);
            atomicAdd(agg + (size_t)dn * 64 + lane, hf ? aH : aL);
        }
    }
}

// ---- x_new = tanh(agg + x @ root + bias); root preloaded to regs (no LDS) ----
__global__ __launch_bounds__(256, 4) void node_kernel(const float* __restrict__ x,
                                                      float* __restrict__ agg,
                                                      const u32* __restrict__ Rp,
                                                      const float* __restrict__ bias, int N) {
    const int lane = threadIdx.x & 63;
    const int hf = lane >> 5;
    float2 rv[32];
    {
        const uint4* rrow = (const uint4*)(Rp + lane * 32);
#pragma unroll
        for (int c = 0; c < 8; ++c) {
            const uint4 wq = rrow[c];
            rv[c * 4 + 0] = h2pair(wq.x); rv[c * 4 + 1] = h2pair(wq.y);
            rv[c * 4 + 2] = h2pair(wq.z); rv[c * 4 + 3] = h2pair(wq.w);
        }
    }
    const float bl = bias[lane];
    int wave = blockIdx.x * 4 + (threadIdx.x >> 6);
    const int nw = gridDim.x * 4;
    for (int n = wave; n < N; n += nw) {
        const float* xr = x + (size_t)n * 64 + hf * 32;
        float aL = 0.f, aH = 0.f;
#pragma unroll
        for (int q = 0; q < 8; ++q) {
            const float4 xv = *(const float4*)(xr + q * 4);
            aL += xv.x * rv[q * 4 + 0].x; aH += xv.x * rv[q * 4 + 0].y;
            aL += xv.y * rv[q * 4 + 1].x; aH += xv.y * rv[q * 4 + 1].y;
            aL += xv.z * rv[q * 4 + 2].x; aH += xv.z * rv[q * 4 + 2].y;
            aL += xv.w * rv[q * 4 + 3].x; aH += xv.w * rv[q * 4 + 3].y;
        }
        aL += __shfl_xor(aL, 32, 64);
        aH += __shfl_xor(aH, 32, 64);
        const float v = hf ? aH : aL;
        const size_t o = (size_t)n * 64 + lane;
        agg[o] = tanhf(agg[o] + v + bl);
    }
}

// ---- gather sequence rows -> f32 output column block l ----
__global__ __launch_bounds__(256) void gather_seq_kernel(const float* __restrict__ xc,
                                                         const int* __restrict__ seqs,
                                                         float* __restrict__ out_seq, int l) {
    const int lane = threadIdx.x & 63;
    int wave = blockIdx.x * 4 + (threadIdx.x >> 6);
    const int nw = gridDim.x * 4;
    for (int p = wave; p < BATCH * SEQL; p += nw) {
        const int idx = seqs[p];
        out_seq[(size_t)p * TD + l * 64 + lane] = xc[(size_t)idx * 64 + lane];
    }
}

// ---- per-batch: user row (f32 out) and msum = sum_t seq rows ----
__global__ __launch_bounds__(256) void user_msum_kernel(const float* __restrict__ xc,
                                                        const int* __restrict__ users,
                                                        const int* __restrict__ seqs,
                                                        float* __restrict__ msum,
                                                        float* __restrict__ out_user, int l) {
    const int lane = threadIdx.x & 63;
    int wave = blockIdx.x * 4 + (threadIdx.x >> 6);
    const int nw = gridDim.x * 4;
    for (int b = wave; b < BATCH; b += nw) {
        out_user[(size_t)b * TD + l * 64 + lane] = xc[(size_t)users[b] * 64 + lane];
        float m = 0.f;
        for (int t = 0; t < SEQL; ++t)
            m += xc[(size_t)seqs[b * SEQL + t] * 64 + lane];
        msum[(size_t)b * TD + l * 64 + lane] = m;
    }
}

// ---- final: s = msum @ WV (attention collapsed); res = pw.(user+s) + pb ----
__global__ __launch_bounds__(384) void final_kernel(const float* __restrict__ msum,
                                                    const float* __restrict__ user_f32,
                                                    const float* __restrict__ WV,
                                                    const float* __restrict__ pw,
                                                    const float* __restrict__ pb,
                                                    const int* __restrict__ items,
                                                    float* __restrict__ out_res) {
    __shared__ float ms[TD];
    __shared__ float uL[TD];
    const int b = blockIdx.x;
    const int o = threadIdx.x;
    ms[o] = msum[(size_t)b * TD + o];
    __syncthreads();
    float sv = 0.f;
#pragma unroll 4
    for (int d = 0; d < TD; ++d) sv += ms[d] * WV[d * TD + o];
    uL[o] = user_f32[(size_t)b * TD + o] + sv;
    __syncthreads();
    const int w = threadIdx.x >> 6, lane = threadIdx.x & 63;
    for (int k = w; k < NPRED; k += 6) {
        const int item = items[b * NPRED + k];
        const float* pwr = pw + (size_t)item * TD;
        float a = 0.f;
#pragma unroll
        for (int d = lane; d < TD; d += 64) a += pwr[d] * uL[d];
#pragma unroll
        for (int off = 32; off; off >>= 1) a += __shfl_down(a, off, 64);
        if (lane == 0) out_res[b * NPRED + k] = a + pb[item];
    }
}

extern "C" void kernel_launch(void* const* d_in, const int* in_sizes, int n_in,
                              void* d_out, int out_size, void* d_ws, size_t ws_size,
                              hipStream_t stream) {
    const float* node_emb  = (const float*)d_in[0];
    const float* predict_w = (const float*)d_in[1];
    const float* predict_b = (const float*)d_in[2];
    const float* basis     = (const float*)d_in[3];
    const float* comp      = (const float*)d_in[4];
    const float* root      = (const float*)d_in[5];
    const float* bias      = (const float*)d_in[6];
    const float* sbasis    = (const float*)d_in[7];
    const float* scomp     = (const float*)d_in[8];
    const float* sroot     = (const float*)d_in[9];
    const float* sbias     = (const float*)d_in[10];
    const float* WV        = (const float*)d_in[13];   // WQ/WK dead (softmax collapse)
    const int* users       = (const int*)d_in[14];
    const int* seqs        = (const int*)d_in[15];
    const int* items       = (const int*)d_in[16];
    const int* eidx        = (const int*)d_in[17];
    const int* etyp        = (const int*)d_in[18];
    const int* seidx       = (const int*)d_in[20];
    const int* setyp       = (const int*)d_in[21];

    const size_t NROW = (size_t)(NNODE + 1) * 64;     // +1 trash row
    float* xA    = (float*)d_ws;                      // [NROW]
    float* xB    = xA + NROW;                         // [NROW]
    u32*   Wp    = (u32*)(xB + NROW);                 // [8*64*32]
    u32*   Rp    = Wp + NREL * 64 * 32;               // [64*32]
    float* msum  = (float*)(Rp + 64 * 32);            // [BATCH*TD]
    int*   ctl   = (int*)(msum + (size_t)BATCH * TD); // [64]: cntB8 curB8 cntS8 curS8 poffB9 poffS9
    int*   cntB  = ctl,      *curB = ctl + 8;
    int*   cntS  = ctl + 16, *curS = ctl + 24;
    int*   poffB = ctl + 32, *poffS = ctl + 41;
    int*   sidxB = ctl + 64;                          // [NEDGE+64]
    int*   sidxS = sidxB + (NEDGE + 64);              // [NSEDGE+64]
    // total ws ~83.3 MB

    float* out      = (float*)d_out;
    float* out_res  = out;                            // [BATCH*NPRED]
    float* out_user = out + BATCH * NPRED;            // [BATCH*TD]
    float* out_seq  = out_user + (size_t)BATCH * TD;  // [BATCH*SEQL*TD]

    // ---- sort both edge lists by relation (once; reused across 3 layers each) ----
    hipMemsetAsync(ctl, 0, 32 * sizeof(int), stream);
    fill_kernel<<<512, 256, 0, stream>>>(sidxB, NEDGE + 64);
    fill_kernel<<<256, 256, 0, stream>>>(sidxS, NSEDGE + 64);
    hist_kernel<<<512, 256, 0, stream>>>(etyp, NEDGE, cntB);
    hist_kernel<<<256, 256, 0, stream>>>(setyp, NSEDGE, cntS);
    offs_kernel<<<1, 1, 0, stream>>>(cntB, cntS, poffB, poffS);
    scatter_kernel<<<512, 256, 0, stream>>>(etyp, NEDGE, curB, poffB, sidxB);
    scatter_kernel<<<256, 256, 0, stream>>>(setyp, NSEDGE, curS, poffS, sidxS);

    const float* xc = node_emb;                       // layer 0 input
    for (int l = 0; l < 6; ++l) {
        const float *bs, *cp, *rt, *bi;
        const int *es, *ed, *si, *po;
        if (l < 3) {
            bs = basis  + (size_t)l * NB * DIM * DIM;
            cp = comp   + l * NREL * NB;
            rt = root   + l * DIM * DIM;
            bi = bias   + l * DIM;
            es = eidx; ed = eidx + NEDGE; si = sidxB; po = poffB;
        } else {
            const int m = l - 3;
            bs = sbasis + (size_t)m * NB * DIM * DIM;
            cp = scomp  + m * NREL * NB;
            rt = sroot  + m * DIM * DIM;
            bi = sbias  + m * DIM;
            es = seidx; ed = seidx + NSEDGE; si = sidxS; po = poffS;
        }
        float* xg = (l & 1) ? xB : xA;
        wpack_kernel<<<64, 256, 0, stream>>>(cp, bs, Wp);
        rpack_kernel<<<8, 256, 0, stream>>>(rt, Rp);
        hipMemsetAsync(xg, 0, (size_t)NNODE * DIM * sizeof(float), stream);
        edge_kernel<<<512, 512, 0, stream>>>(xc, Wp, si, es, ed, po, xg);
        node_kernel<<<512, 256, 0, stream>>>(xc, xg, Rp, bi, NNODE);
        gather_seq_kernel<<<320, 256, 0, stream>>>(xg, seqs, out_seq, l);
        user_msum_kernel<<<256, 256, 0, stream>>>(xg, users, seqs, msum, out_user, l);
        xc = xg;
    }

    final_kernel<<<BATCH, 384, 0, stream>>>(msum, out_user, WV, predict_w, predict_b,
                                            items, out_res);
}